// Round 10
// baseline (126.411 us; speedup 1.0000x reference)
//
#include <hip/hip_runtime.h>

#define BATCHES 4
#define NPTS    8192
#define INF32   3.0e38f

typedef _Float16 f16x8  __attribute__((ext_vector_type(8)));
typedef float    f32x16 __attribute__((ext_vector_type(16)));

// ---------------- prep: pack A-format and B-format 16-slot f16 vectors ----
// A-vec (pt p):  [ph0..2, pl0..2, ph0..2, qh, ql, 1, 1, 0,0,0]
// B-vec (pt p):  [-2ph0..2, -2ph0..2, -2pl0..2, 1, 1, qh, ql, 0,0,0]
// dot(Avec(u), Bvec(v)) = |u|^2 + |v|^2 - 2*(uh.vh + ul.vh + uh.vl)  (err ~1e-5)
__device__ inline void fsplit(float v, _Float16& h, _Float16& l) {
    h = (_Float16)v;
    l = (_Float16)(v - (float)h);
}

__device__ inline void pack_point(float p0, float p1, float p2,
                                  _Float16* __restrict__ avec,
                                  _Float16* __restrict__ bvec)
{
    _Float16 h[3], l[3];
    fsplit(p0, h[0], l[0]); fsplit(p1, h[1], l[1]); fsplit(p2, h[2], l[2]);
    float q = fmaf(p2, p2, fmaf(p1, p1, p0 * p0));
    _Float16 qh, ql;
    fsplit(q, qh, ql);

    __align__(16) _Float16 av[16];
    __align__(16) _Float16 bv[16];
    #pragma unroll
    for (int k = 0; k < 3; ++k) {
        av[k]     = h[k];
        av[3 + k] = l[k];
        av[6 + k] = h[k];
        bv[k]     = (_Float16)(-2.0f * (float)h[k]);
        bv[3 + k] = bv[k];
        bv[6 + k] = (_Float16)(-2.0f * (float)l[k]);
    }
    av[9] = qh; av[10] = ql; av[11] = (_Float16)1.0f; av[12] = (_Float16)1.0f;
    bv[9] = (_Float16)1.0f; bv[10] = (_Float16)1.0f; bv[11] = qh; bv[12] = ql;
    av[13] = av[14] = av[15] = (_Float16)0.0f;
    bv[13] = bv[14] = bv[15] = (_Float16)0.0f;

    ((int4*)avec)[0] = ((int4*)av)[0]; ((int4*)avec)[1] = ((int4*)av)[1];
    ((int4*)bvec)[0] = ((int4*)bv)[0]; ((int4*)bvec)[1] = ((int4*)bv)[1];
}

__global__ __launch_bounds__(256) void chamfer_prep(
    const float* __restrict__ x, const float* __restrict__ y,
    _Float16* __restrict__ pAx, _Float16* __restrict__ pBx,
    _Float16* __restrict__ pAy, _Float16* __restrict__ pBy,
    int* __restrict__ mininit /* 65536 ints */)
{
    int i = blockIdx.x * 256 + threadIdx.x;     // point id 0..32767
    mininit[i]         = 0x7F7F7F7F;
    mininit[i + 32768] = 0x7F7F7F7F;

    const float* xp = x + (size_t)i * 3;
    const float* yp = y + (size_t)i * 3;
    pack_point(xp[0], xp[1], xp[2], pAx + (size_t)i * 16, pBx + (size_t)i * 16);
    pack_point(yp[0], yp[1], yp[2], pAy + (size_t)i * 16, pBy + (size_t)i * 16);
}

// ---------------- main: double-GEMM, 2-deep software-pipelined -------------
// grid 1024 = dir(2) x batch(4) x strip(64: 128 rows) x chunk(2: 4096 cols)
// wave owns 32 rows (one A-tile), loops 128 col-tiles as 64 pairs.
// Pipeline: iteration p min-processes pair issued LAST iteration while this
// iteration's MFMAs execute; B-frags loaded one iteration ahead.
// Live: R0,R1,S0,S1 (64 VGPR) + rmin[16] + 4 b-frags (16) + af (4) ~ 110.
// A-frag: lane(row=l&31, k=(l>>5)*8+i); B-frag: lane(col=l&31, same k).
// D: col=l&31, row=(reg&3)+8*(reg>>2)+4*(l>>5)  [m74/m101].
__global__ __launch_bounds__(256, 4) void chamfer_mfma(
    const _Float16* __restrict__ pAx, const _Float16* __restrict__ pBx,
    const _Float16* __restrict__ pAy, const _Float16* __restrict__ pBy,
    float* __restrict__ minall /* [2][4][8192]: dir0 x-mins, dir1 y-mins */)
{
    int bid   = blockIdx.x;
    int dir   = bid >> 9;
    int rem   = bid & 511;
    int b     = rem >> 7;
    int rem2  = rem & 127;
    int strip = rem2 >> 1;         // 0..63 -> 128 rows
    int chunk = rem2 & 1;          // 0..1  -> 4096 cols
    int tid   = threadIdx.x;
    int wv    = tid >> 6, lane = tid & 63;
    int lo    = lane & 31, hi = lane >> 5;

    const _Float16* Adata = ((dir == 0) ? pAx : pAy) + (size_t)b * NPTS * 16;
    const _Float16* Bdata = ((dir == 0) ? pBy : pBx) + (size_t)b * NPTS * 16;
    float* outMin = minall + ((size_t)dir << 15) + (size_t)b * NPTS;

    int rw = strip * 128 + wv * 32;    // wave's row base (one 32-row tile)
    int c0 = chunk * 4096;             // block's col base (128 col-tiles)

    f16x8 af = *(const f16x8*)(Adata + (size_t)(rw + lo) * 16 + hi * 8);

    float rmin[16];
    #pragma unroll
    for (int r = 0; r < 16; ++r) rmin[r] = INF32;

    const f32x16 zero = {0.f,0.f,0.f,0.f,0.f,0.f,0.f,0.f,
                         0.f,0.f,0.f,0.f,0.f,0.f,0.f,0.f};

    auto loadB = [&](int t) -> f16x8 {   // t = col-tile index 0..127
        return *(const f16x8*)(Bdata + (size_t)(c0 + (t << 5) + lo) * 16 + hi * 8);
    };

#define MIN16(P0, P1)                                                  \
    _Pragma("unroll")                                                  \
    for (int r = 0; r < 16; ++r)                                       \
        rmin[r] = fminf(fminf(P0[r], P1[r]), rmin[r]);   /* v_min3 */

    // prologue: pairs 0,1 in flight; b-regs refilled for pairs 2,3
    f16x8 bA0 = loadB(0), bA1 = loadB(1), bB0 = loadB(2), bB1 = loadB(3);
    f32x16 R0 = __builtin_amdgcn_mfma_f32_32x32x16_f16(af, bA0, zero, 0, 0, 0);
    f32x16 R1 = __builtin_amdgcn_mfma_f32_32x32x16_f16(af, bA1, zero, 0, 0, 0);
    f32x16 S0 = __builtin_amdgcn_mfma_f32_32x32x16_f16(af, bB0, zero, 0, 0, 0);
    f32x16 S1 = __builtin_amdgcn_mfma_f32_32x32x16_f16(af, bB1, zero, 0, 0, 0);
    bA0 = loadB(4); bA1 = loadB(5); bB0 = loadB(6); bB1 = loadB(7);

    // iter p: process pairs 2p (R), 2p+1 (S); issue pairs 2p+2, 2p+3;
    //         load tiles for pairs 2p+4, 2p+5 (indices 4p+8..4p+11 <= 127).
    #pragma unroll 1
    for (int p = 0; p < 30; ++p) {
        MIN16(R0, R1)                                   // pair 2p
        R0 = __builtin_amdgcn_mfma_f32_32x32x16_f16(af, bA0, zero, 0, 0, 0);
        R1 = __builtin_amdgcn_mfma_f32_32x32x16_f16(af, bA1, zero, 0, 0, 0);
        bA0 = loadB(4 * p + 8); bA1 = loadB(4 * p + 9);
        MIN16(S0, S1)                                   // pair 2p+1
        S0 = __builtin_amdgcn_mfma_f32_32x32x16_f16(af, bB0, zero, 0, 0, 0);
        S1 = __builtin_amdgcn_mfma_f32_32x32x16_f16(af, bB1, zero, 0, 0, 0);
        bB0 = loadB(4 * p + 10); bB1 = loadB(4 * p + 11);
    }

    // epilogue: pairs 60..63
    MIN16(R0, R1)                                       // pair 60
    R0 = __builtin_amdgcn_mfma_f32_32x32x16_f16(af, bA0, zero, 0, 0, 0);
    R1 = __builtin_amdgcn_mfma_f32_32x32x16_f16(af, bA1, zero, 0, 0, 0);
    MIN16(S0, S1)                                       // pair 61
    S0 = __builtin_amdgcn_mfma_f32_32x32x16_f16(af, bB0, zero, 0, 0, 0);
    S1 = __builtin_amdgcn_mfma_f32_32x32x16_f16(af, bB1, zero, 0, 0, 0);
    MIN16(R0, R1)                                       // pair 62
    MIN16(S0, S1)                                       // pair 63
#undef MIN16

    // fold row-mins across the 32 col positions (lane bits 0-4), atomicMin
    #pragma unroll
    for (int r = 0; r < 16; ++r) {
        float v = rmin[r];
        v = fminf(v, __shfl_xor(v, 1, 64));
        v = fminf(v, __shfl_xor(v, 2, 64));
        v = fminf(v, __shfl_xor(v, 4, 64));
        v = fminf(v, __shfl_xor(v, 8, 64));
        v = fminf(v, __shfl_xor(v, 16, 64));
        if (lo == 0) {
            int rr = (r & 3) + ((r >> 2) << 3) + (hi << 2);
            atomicMin((int*)&outMin[rw + rr], __float_as_int(fmaxf(v, 0.f)));
        }
    }
}

// ---------------- final reduction (fixed-tree, deterministic) --------------
__global__ __launch_bounds__(256) void chamfer_reduce1(
    const float* __restrict__ minbuf, double* __restrict__ partials)
{
    int base = blockIdx.x * 1024 + threadIdx.x * 4;
    float4 v = *reinterpret_cast<const float4*>(minbuf + base);
    double s = ((double)v.x + (double)v.y) + ((double)v.z + (double)v.w);
    #pragma unroll
    for (int off = 32; off > 0; off >>= 1) s += __shfl_down(s, off, 64);
    __shared__ double sd[4];
    int wid = threadIdx.x >> 6;
    if ((threadIdx.x & 63) == 0) sd[wid] = s;
    __syncthreads();
    if (threadIdx.x == 0)
        partials[blockIdx.x] = (sd[0] + sd[1]) + (sd[2] + sd[3]);
}

__global__ __launch_bounds__(64) void chamfer_reduce2(
    const double* __restrict__ partials, float* __restrict__ out)
{
    double s = partials[threadIdx.x];
    #pragma unroll
    for (int off = 32; off > 0; off >>= 1) s += __shfl_down(s, off, 64);
    if (threadIdx.x == 0)
        out[0] = (float)(s / (double)(BATCHES * NPTS));
}

extern "C" void kernel_launch(void* const* d_in, const int* in_sizes, int n_in,
                              void* d_out, int out_size, void* d_ws, size_t ws_size,
                              hipStream_t stream)
{
    const float* x = (const float*)d_in[0];
    const float* y = (const float*)d_in[1];
    float* out = (float*)d_out;

    // ws layout (~4.5 MB):
    float*    minall = (float*)d_ws;                       // 65536 f = 256 KB
    _Float16* pAx = (_Float16*)(minall + 65536);           // 1 MB each
    _Float16* pBx = pAx + (size_t)BATCHES * NPTS * 16;
    _Float16* pAy = pBx + (size_t)BATCHES * NPTS * 16;
    _Float16* pBy = pAy + (size_t)BATCHES * NPTS * 16;
    double*   partials = (double*)(pBy + (size_t)BATCHES * NPTS * 16);

    chamfer_prep<<<BATCHES * NPTS / 256, 256, 0, stream>>>(
        x, y, pAx, pBx, pAy, pBy, (int*)minall);
    chamfer_mfma<<<1024, 256, 0, stream>>>(pAx, pBx, pAy, pBy, minall);
    chamfer_reduce1<<<64, 256, 0, stream>>>(minall, partials);
    chamfer_reduce2<<<1, 64, 0, stream>>>(partials, out);
}

// Round 11
// 36.531 us; speedup vs baseline: 3.4604x; 3.4604x over previous
//
#include <hip/hip_runtime.h>

#define BATCHES 4
#define NPTS    8192
#define INF32   3.0e38f

typedef _Float16 f16x8  __attribute__((ext_vector_type(8)));
typedef float    f32x16 __attribute__((ext_vector_type(16)));

// ---------------- prep: pack A-format and B-format 16-slot f16 vectors ----
// A-vec (pt p):  [ph0..2, pl0..2, ph0..2, qh, ql, 1, 1, 0,0,0]
// B-vec (pt p):  [-2ph0..2, -2ph0..2, -2pl0..2, 1, 1, qh, ql, 0,0,0]
// dot(Avec(u), Bvec(v)) = |u|^2 + |v|^2 - 2*(uh.vh + ul.vh + uh.vl)  (err ~1e-5)
__device__ inline void fsplit(float v, _Float16& h, _Float16& l) {
    h = (_Float16)v;
    l = (_Float16)(v - (float)h);
}

__device__ inline void pack_point(float p0, float p1, float p2,
                                  _Float16* __restrict__ avec,
                                  _Float16* __restrict__ bvec)
{
    _Float16 h[3], l[3];
    fsplit(p0, h[0], l[0]); fsplit(p1, h[1], l[1]); fsplit(p2, h[2], l[2]);
    float q = fmaf(p2, p2, fmaf(p1, p1, p0 * p0));
    _Float16 qh, ql;
    fsplit(q, qh, ql);

    __align__(16) _Float16 av[16];
    __align__(16) _Float16 bv[16];
    #pragma unroll
    for (int k = 0; k < 3; ++k) {
        av[k]     = h[k];
        av[3 + k] = l[k];
        av[6 + k] = h[k];
        bv[k]     = (_Float16)(-2.0f * (float)h[k]);
        bv[3 + k] = bv[k];
        bv[6 + k] = (_Float16)(-2.0f * (float)l[k]);
    }
    av[9] = qh; av[10] = ql; av[11] = (_Float16)1.0f; av[12] = (_Float16)1.0f;
    bv[9] = (_Float16)1.0f; bv[10] = (_Float16)1.0f; bv[11] = qh; bv[12] = ql;
    av[13] = av[14] = av[15] = (_Float16)0.0f;
    bv[13] = bv[14] = bv[15] = (_Float16)0.0f;

    ((int4*)avec)[0] = ((int4*)av)[0]; ((int4*)avec)[1] = ((int4*)av)[1];
    ((int4*)bvec)[0] = ((int4*)bv)[0]; ((int4*)bvec)[1] = ((int4*)bv)[1];
}

__global__ __launch_bounds__(256) void chamfer_prep(
    const float* __restrict__ x, const float* __restrict__ y,
    _Float16* __restrict__ pAx, _Float16* __restrict__ pBx,
    _Float16* __restrict__ pAy, _Float16* __restrict__ pBy,
    int* __restrict__ mininit /* 65536 ints */)
{
    int i = blockIdx.x * 256 + threadIdx.x;     // point id 0..32767
    mininit[i]         = 0x7F7F7F7F;
    mininit[i + 32768] = 0x7F7F7F7F;

    const float* xp = x + (size_t)i * 3;
    const float* yp = y + (size_t)i * 3;
    pack_point(xp[0], xp[1], xp[2], pAx + (size_t)i * 16, pBx + (size_t)i * 16);
    pack_point(yp[0], yp[1], yp[2], pAy + (size_t)i * 16, pBy + (size_t)i * 16);
}

// ---------------- main: dual GEMM, LDS-staged B, register row-min ----------
// grid 512 = dir(2) x batch(4) x strip(16: 512 rows) x chunk(4: 2048 cols)
// 512 threads = 8 waves; each wave owns 64 rows (2 A-tiles af0/af1).
// B-chunk (64 tiles x 1 KB = 64 KB) staged to LDS once (reg-staged, linear
// [tile][lane] layout -> stride-16B ds_read_b128, conflict-free), then the
// K-loop is pure {ds_read, MFMA, v_min3} -- no VMEM latency in the loop.
// A-frag: lane(row=l&31, k=(l>>5)*8+i); B-frag: lane(col=l&31, same k).
// D: col=l&31, row=(reg&3)+8*(reg>>2)+4*(l>>5)  [m74/m101].
__global__ __launch_bounds__(512, 4) void chamfer_mfma(
    const _Float16* __restrict__ pAx, const _Float16* __restrict__ pBx,
    const _Float16* __restrict__ pAy, const _Float16* __restrict__ pBy,
    float* __restrict__ minall /* [2][4][8192]: dir0 x-mins, dir1 y-mins */)
{
    int bid   = blockIdx.x;
    int dir   = bid >> 8;
    int rem   = bid & 255;
    int b     = rem >> 6;
    int rem2  = rem & 63;
    int strip = rem2 >> 2;         // 0..15 -> 512 rows
    int chunk = rem2 & 3;          // 0..3  -> 2048 cols (64 col-tiles)
    int tid   = threadIdx.x;
    int wv    = tid >> 6, lane = tid & 63;
    int lo    = lane & 31, hi = lane >> 5;

    const _Float16* Adata = ((dir == 0) ? pAx : pAy) + (size_t)b * NPTS * 16;
    const _Float16* Bdata = ((dir == 0) ? pBy : pBx) + (size_t)b * NPTS * 16;
    float* outMin = minall + ((size_t)dir << 15) + (size_t)b * NPTS;

    int rw = strip * 512 + wv * 64;    // wave's row base (2 tiles of 32)
    int c0 = chunk * 2048;             // block's col base

    // ---- stage B-chunk: tile t, slot lane -> sB[t*512 + lane*8] (halves)
    __shared__ __align__(16) _Float16 sB[64 * 512];   // 64 KB
    #pragma unroll
    for (int tt = 0; tt < 8; ++tt) {
        int t = wv + tt * 8;           // wave wv stages tiles wv, wv+8, ...
        const int4* src = (const int4*)(Bdata +
            ((size_t)(c0 + (t << 5) + lo) << 4) + (hi << 3));
        *(int4*)(sB + (size_t)t * 512 + lane * 8) = *src;
    }
    __syncthreads();

    f16x8 af0 = *(const f16x8*)(Adata + (size_t)(rw + lo) * 16 + hi * 8);
    f16x8 af1 = *(const f16x8*)(Adata + (size_t)(rw + 32 + lo) * 16 + hi * 8);

    float rmin0[16], rmin1[16];
    #pragma unroll
    for (int r = 0; r < 16; ++r) { rmin0[r] = INF32; rmin1[r] = INF32; }

    const f32x16 zero = {0.f,0.f,0.f,0.f,0.f,0.f,0.f,0.f,
                         0.f,0.f,0.f,0.f,0.f,0.f,0.f,0.f};

    auto ldsB = [&](int t) -> f16x8 {
        return *(const f16x8*)(sB + ((size_t)(t & 63) << 9) + lane * 8);
    };

    f16x8 bc0 = ldsB(0), bc1 = ldsB(1);
    #pragma unroll 1
    for (int t = 0; t < 64; t += 2) {
        f16x8 nb0 = ldsB(t + 2);
        f16x8 nb1 = ldsB(t + 3);
        f32x16 A0 = __builtin_amdgcn_mfma_f32_32x32x16_f16(af0, bc0, zero, 0, 0, 0);
        f32x16 A1 = __builtin_amdgcn_mfma_f32_32x32x16_f16(af0, bc1, zero, 0, 0, 0);
        #pragma unroll
        for (int r = 0; r < 16; ++r)
            rmin0[r] = fminf(fminf(A0[r], A1[r]), rmin0[r]);   // v_min3
        f32x16 B0 = __builtin_amdgcn_mfma_f32_32x32x16_f16(af1, bc0, zero, 0, 0, 0);
        f32x16 B1 = __builtin_amdgcn_mfma_f32_32x32x16_f16(af1, bc1, zero, 0, 0, 0);
        #pragma unroll
        for (int r = 0; r < 16; ++r)
            rmin1[r] = fminf(fminf(B0[r], B1[r]), rmin1[r]);   // v_min3
        bc0 = nb0; bc1 = nb1;
    }

    // fold row-mins across the 32 col positions (lane bits 0-4), atomicMin
    #pragma unroll
    for (int r = 0; r < 16; ++r) {
        float v = rmin0[r];
        v = fminf(v, __shfl_xor(v, 1, 64));
        v = fminf(v, __shfl_xor(v, 2, 64));
        v = fminf(v, __shfl_xor(v, 4, 64));
        v = fminf(v, __shfl_xor(v, 8, 64));
        v = fminf(v, __shfl_xor(v, 16, 64));
        float w = rmin1[r];
        w = fminf(w, __shfl_xor(w, 1, 64));
        w = fminf(w, __shfl_xor(w, 2, 64));
        w = fminf(w, __shfl_xor(w, 4, 64));
        w = fminf(w, __shfl_xor(w, 8, 64));
        w = fminf(w, __shfl_xor(w, 16, 64));
        if (lo == 0) {
            int rr = (r & 3) + ((r >> 2) << 3) + (hi << 2);
            atomicMin((int*)&outMin[rw + rr],      __float_as_int(fmaxf(v, 0.f)));
            atomicMin((int*)&outMin[rw + 32 + rr], __float_as_int(fmaxf(w, 0.f)));
        }
    }
}

// ---------------- final reduction (fixed-tree, deterministic) --------------
__global__ __launch_bounds__(256) void chamfer_reduce1(
    const float* __restrict__ minbuf, double* __restrict__ partials)
{
    int base = blockIdx.x * 1024 + threadIdx.x * 4;
    float4 v = *reinterpret_cast<const float4*>(minbuf + base);
    double s = ((double)v.x + (double)v.y) + ((double)v.z + (double)v.w);
    #pragma unroll
    for (int off = 32; off > 0; off >>= 1) s += __shfl_down(s, off, 64);
    __shared__ double sd[4];
    int wid = threadIdx.x >> 6;
    if ((threadIdx.x & 63) == 0) sd[wid] = s;
    __syncthreads();
    if (threadIdx.x == 0)
        partials[blockIdx.x] = (sd[0] + sd[1]) + (sd[2] + sd[3]);
}

__global__ __launch_bounds__(64) void chamfer_reduce2(
    const double* __restrict__ partials, float* __restrict__ out)
{
    double s = partials[threadIdx.x];
    #pragma unroll
    for (int off = 32; off > 0; off >>= 1) s += __shfl_down(s, off, 64);
    if (threadIdx.x == 0)
        out[0] = (float)(s / (double)(BATCHES * NPTS));
}

extern "C" void kernel_launch(void* const* d_in, const int* in_sizes, int n_in,
                              void* d_out, int out_size, void* d_ws, size_t ws_size,
                              hipStream_t stream)
{
    const float* x = (const float*)d_in[0];
    const float* y = (const float*)d_in[1];
    float* out = (float*)d_out;

    // ws layout (~4.5 MB):
    float*    minall = (float*)d_ws;                       // 65536 f = 256 KB
    _Float16* pAx = (_Float16*)(minall + 65536);           // 1 MB each
    _Float16* pBx = pAx + (size_t)BATCHES * NPTS * 16;
    _Float16* pAy = pBx + (size_t)BATCHES * NPTS * 16;
    _Float16* pBy = pAy + (size_t)BATCHES * NPTS * 16;
    double*   partials = (double*)(pBy + (size_t)BATCHES * NPTS * 16);

    chamfer_prep<<<BATCHES * NPTS / 256, 256, 0, stream>>>(
        x, y, pAx, pBx, pAy, pBy, (int*)minall);
    chamfer_mfma<<<512, 512, 0, stream>>>(pAx, pBx, pAy, pBy, minall);
    chamfer_reduce1<<<64, 256, 0, stream>>>(minall, partials);
    chamfer_reduce2<<<1, 64, 0, stream>>>(partials, out);
}